// Round 2
// baseline (174.006 us; speedup 1.0000x reference)
//
#include <hip/hip_runtime.h>
#include <math.h>

#define HASH_PRIME 2654435761u
#define TMASK 32767u
#define NPB 128
#define HWORDS 35           // unsigned per LDS row in legacy stageB (odd -> conflict-free)
#define HSTRIDE 68          // ushorts per LDS row in fallback (legacy)
#define CHUNK 65536         // 1M/65536 = 16 -> 16*32 = 512 blocks = 2/CU queued (load balance)

typedef float vf2 __attribute__((ext_vector_type(2)));
typedef float vf4 __attribute__((ext_vector_type(4)));
typedef unsigned vu2 __attribute__((ext_vector_type(2)));
typedef unsigned vu4 __attribute__((ext_vector_type(4)));

__device__ __forceinline__ unsigned pack_bf16(float a, float b) {
    return (__float_as_uint(a) >> 16) | (__float_as_uint(b) & 0xffff0000u);
}
__device__ __forceinline__ float bf_lo(unsigned w) { return __uint_as_float(w << 16); }
__device__ __forceinline__ float bf_hi(unsigned w) { return __uint_as_float(w & 0xffff0000u); }

// ---------------- kernel 1: coords + vect prepass (+ table bf16 pre-pack) ----------------
__global__ __launch_bounds__(256)
void prepass(const float* __restrict__ x,
             const float* __restrict__ t1, const float* __restrict__ t2,
             unsigned* __restrict__ cD, unsigned* __restrict__ cV,
             vf4* __restrict__ vect, unsigned* __restrict__ Tp,
             int n, int nbp)
{
    if ((int)blockIdx.x >= nbp) {
        const int tb = (int)blockIdx.x - nbp;
        const float* src = (tb < 16) ? (t1 + (size_t)tb * 65536)
                                     : (t2 + (size_t)(tb - 16) * 65536);
        const vf4* s4 = (const vf4*)src;
        vu2* dst = (vu2*)(Tp + (size_t)tb * 32768);
        #pragma unroll 8
        for (int j = 0; j < 64; ++j) {
            const int k = j * 256 + (int)threadIdx.x;
            vf4 e = s4[k];                       // entries 2k, 2k+1
            vu2 w; w.x = pack_bf16(e.x, e.y); w.y = pack_bf16(e.z, e.w);
            dst[k] = w;
        }
        return;
    }

    const int i = blockIdx.x * 256 + threadIdx.x;
    if (i >= n) return;
    const float* xi = x + (long long)i * 6;
    vf2 p0 = __builtin_nontemporal_load((const vf2*)(xi + 0));
    vf2 p1 = __builtin_nontemporal_load((const vf2*)(xi + 2));
    vf2 p2 = __builtin_nontemporal_load((const vf2*)(xi + 4));
    float ox = p0.x, oy = p0.y, oz = p1.x;
    float dx = p1.y - ox, dy = p2.x - oy, dz = p2.y - oz;

    float nd = sqrtf(dx * dx + dy * dy + dz * dz);
    float invd = 1.0f / fmaxf(nd, 1e-12f);
    dx *= invd; dy *= invd; dz *= invd;

    float th_d = acosf(fminf(fmaxf(dz, -1.f), 1.f));
    float ph_d = atan2f(dy, dx);
    float u_d = (th_d + 3.14159265358979323846f) / 6.28318530717958647692f;
    float v_d = (ph_d + 3.14159265358979323846f) / 6.28318530717958647692f;

    float cx = oy * dz - oz * dy;
    float cy = oz * dx - ox * dz;
    float cz = ox * dy - oy * dx;
    float vx = dy * cz - dz * cy;
    float vy = dz * cx - dx * cz;
    float vz = dx * cy - dy * cx;

    float nv = sqrtf(vx * vx + vy * vy + vz * vz);
    float invv = 1.0f / fmaxf(nv, 1e-12f);
    float wx = vx * invv, wy = vy * invv, wz = vz * invv;
    float th_v = acosf(fminf(fmaxf(wz, -1.f), 1.f));
    float ph_v = atan2f(wy, wx);
    float u_v = (th_v + 3.14159265358979323846f) / 6.28318530717958647692f;
    float v_v = (ph_v + 3.14159265358979323846f) / 6.28318530717958647692f;

    unsigned ud = (unsigned)fminf(fmaxf(u_d, 0.f) * 65536.f, 65535.f);
    unsigned vd = (unsigned)fminf(fmaxf(v_d, 0.f) * 65536.f, 65535.f);
    unsigned uv = (unsigned)fminf(fmaxf(u_v, 0.f) * 65536.f, 65535.f);
    unsigned vv_ = (unsigned)fminf(fmaxf(v_v, 0.f) * 65536.f, 65535.f);
    __builtin_nontemporal_store(ud | (vd << 16), &cD[i]);
    __builtin_nontemporal_store(uv | (vv_ << 16), &cV[i]);
    vf4 vo; vo.x = vx; vo.y = vy; vo.z = vz; vo.w = 0.f;
    __builtin_nontemporal_store(vo, &vect[i]);
}

// ---------------- kernel 2: per-(table,level) LDS-gather ----------------
__device__ __forceinline__ unsigned enc_point(const unsigned* __restrict__ tl,
                                              float rs, unsigned cw)
{
    float pu = (float)(cw & 0xffffu) * rs;
    float pv = (float)(cw >> 16) * rs;
    float fu = floorf(pu), fv = floorf(pv);
    float au = pu - fu, av = pv - fv;
    unsigned cu = (unsigned)fu, cv = (unsigned)fv;
    unsigned h0 = cv * HASH_PRIME;
    unsigned h1 = (cv + 1u) * HASH_PRIME;
    unsigned w00 = tl[(cu ^ h0) & TMASK];
    unsigned w01 = tl[(cu ^ h1) & TMASK];
    unsigned w10 = tl[((cu + 1u) ^ h0) & TMASK];
    unsigned w11 = tl[((cu + 1u) ^ h1) & TMASK];
    float a00 = (1.f - au) * (1.f - av);
    float a01 = (1.f - au) * av;
    float a10 = au * (1.f - av);
    float a11 = au * av;
    float o0 = a00 * bf_lo(w00) + a01 * bf_lo(w01) + a10 * bf_lo(w10) + a11 * bf_lo(w11);
    float o1 = a00 * bf_hi(w00) + a01 * bf_hi(w01) + a10 * bf_hi(w10) + a11 * bf_hi(w11);
    return pack_bf16(o0, o1);
}

// FULL: n % CHUNK == 0, guard-free, F stored TILED [i>>7][tb][i&127]
// !FULL: guarded, F stored linear [tb][i]
template<bool FULL, bool PACKED>
__global__ __launch_bounds__(1024)
void stageA(const float* __restrict__ t1, const float* __restrict__ t2,
            const unsigned* __restrict__ Tp,
            const unsigned* __restrict__ cD, const unsigned* __restrict__ cV,
            unsigned* __restrict__ F, int n)
{
    __shared__ unsigned tl[32768];        // whole level table, bf16-pair packed (128 KB)
    // longest-job-first: y=0,1,2,3,... -> tb = 15,31,14,30,... (fine hashed levels dispatch first)
    const int y = blockIdx.y;
    const int tb = (y & 1) * 16 + (15 - (y >> 1));
    const float resv[16] = {16.f, 20.f, 25.f, 32.f, 40.f, 50.f, 64.f, 80.f,
                            101.f, 128.f, 161.f, 203.f, 256.f, 322.f, 406.f, 512.f};
    const float rs = resv[tb & 15] * (1.f / 65536.f);

    if constexpr (PACKED) {
        const vf4* s4 = (const vf4*)(Tp + (size_t)tb * 32768);
        vf4* tl4 = (vf4*)tl;
        #pragma unroll
        for (int j = 0; j < 8; ++j) {
            const int k = j * 1024 + threadIdx.x;
            tl4[k] = s4[k];
        }
    } else {
        const float* src = (tb < 16) ? (t1 + (size_t)tb * 65536)
                                     : (t2 + (size_t)(tb - 16) * 65536);
        const vf4* src4 = (const vf4*)src;
        vu2* tl2 = (vu2*)tl;
        #pragma unroll
        for (int j = 0; j < 16; ++j) {
            const int k = j * 1024 + threadIdx.x;
            vf4 e = src4[k];
            vu2 w; w.x = pack_bf16(e.x, e.y); w.y = pack_bf16(e.z, e.w);
            tl2[k] = w;
        }
    }
    __syncthreads();

    const unsigned* cc = (tb < 16) ? cD : cV;   // plain loads: L2/L3-reused x16
    const int ibase = blockIdx.x * CHUNK + threadIdx.x;

    if (FULL) {
        const unsigned tb7 = (unsigned)tb << 7;
        #pragma unroll 2
        for (int k = 0; k < CHUNK / 1024; k += 4) {
            const int i0 = ibase + (k + 0) * 1024;
            const int i1 = ibase + (k + 1) * 1024;
            const int i2 = ibase + (k + 2) * 1024;
            const int i3 = ibase + (k + 3) * 1024;
            unsigned c0 = cc[i0];
            unsigned c1 = cc[i1];
            unsigned c2 = cc[i2];
            unsigned c3 = cc[i3];
            unsigned r0 = enc_point(tl, rs, c0);
            unsigned r1 = enc_point(tl, rs, c1);
            unsigned r2 = enc_point(tl, rs, c2);
            unsigned r3 = enc_point(tl, rs, c3);
            // tiled store: [i>>7][tb][i&127] — 256B/wave coalesced
            F[(((unsigned)i0 >> 7) << 12) + tb7 + ((unsigned)i0 & 127u)] = r0;
            F[(((unsigned)i1 >> 7) << 12) + tb7 + ((unsigned)i1 & 127u)] = r1;
            F[(((unsigned)i2 >> 7) << 12) + tb7 + ((unsigned)i2 & 127u)] = r2;
            F[(((unsigned)i3 >> 7) << 12) + tb7 + ((unsigned)i3 & 127u)] = r3;
        }
    } else {
        unsigned* Fo = F + (size_t)tb * (size_t)n;
        #pragma unroll 4
        for (int k = 0; k < CHUNK / 1024; ++k) {
            const int i = ibase + k * 1024;
            if (i < n) {
                unsigned c = cc[i];
                Fo[i] = enc_point(tl, rs, c);
            }
        }
    }
}

// ---------------- kernel 3 (tiled): contiguous F tile -> LDS b128 -> dwordx4 out ----------------
__global__ __launch_bounds__(NPB)
void stageB_t(const unsigned* __restrict__ F, const vf4* __restrict__ vect,
              float* __restrict__ out, int n)
{
    __shared__ __align__(16) unsigned hlds2[32 * 132];   // [c][p], row stride 132 words
    __shared__ float vlds[NPB * 4];
    const int tid = threadIdx.x;
    const long long blk_start = (long long)blockIdx.x * NPB;
    const long long i = blk_start + tid;
    if (i < (long long)n) {
        vf4 vv = __builtin_nontemporal_load(&vect[i]);
        vlds[tid * 4 + 0] = vv.x;
        vlds[tid * 4 + 1] = vv.y;
        vlds[tid * 4 + 2] = vv.z;
    }
    // F tile for this block: 4096 contiguous dwords = [32 levels][128 points]
    {
        const vu4* Ft = (const vu4*)(F + (size_t)blockIdx.x * 4096);
        const int p0 = 4 * (tid & 31);
        #pragma unroll
        for (int j = 0; j < 8; ++j) {
            vu4 w = __builtin_nontemporal_load(&Ft[tid + 128 * j]);
            const int c = 4 * j + (tid >> 5);
            *(vu4*)&hlds2[c * 132 + p0] = w;       // ds_write_b128, conflict-free
        }
    }
    __syncthreads();

    const int rows = (int)(((blk_start + NPB) <= (long long)n) ? NPB : (n - blk_start));
    if (rows <= 0) return;
    const long long base = blk_start * 67ll;
    const int total = rows * 67;
    const unsigned short* hs = (const unsigned short*)hlds2;

    const int nq = total >> 2;
    vf4* out4 = (vf4*)(out + base);
    for (int k = tid; k < nq; k += NPB) {
        vf4 o;
        #pragma unroll
        for (int j = 0; j < 4; ++j) {
            const int e = 4 * k + j;
            const int r = e / 67;
            const int c = e - r * 67;
            float val;
            if (c < 3) val = vlds[r * 4 + c];
            else {
                const int f = c - 3;
                val = __uint_as_float((unsigned)hs[(f >> 1) * 264 + 2 * r + (f & 1)] << 16);
            }
            o[j] = val;
        }
        __builtin_nontemporal_store(o, &out4[k]);
    }
    for (int e = (nq << 2) + tid; e < total; e += NPB) {
        const int r = e / 67;
        const int c = e - r * 67;
        float val;
        if (c < 3) val = vlds[r * 4 + c];
        else {
            const int f = c - 3;
            val = __uint_as_float((unsigned)hs[(f >> 1) * 264 + 2 * r + (f & 1)] << 16);
        }
        __builtin_nontemporal_store(val, &out[base + e]);
    }
}

// ---------------- kernel 3 (legacy linear F layout) ----------------
__global__ __launch_bounds__(NPB)
void stageB(const unsigned* __restrict__ F, const vf4* __restrict__ vect,
            float* __restrict__ out, int n)
{
    __shared__ unsigned hlds[NPB * HWORDS];
    __shared__ float vlds[NPB * 4];
    const int tid = threadIdx.x;
    const long long blk_start = (long long)blockIdx.x * NPB;
    const long long i = blk_start + tid;
    if (i < (long long)n) {
        vf4 vv = vect[i];
        vlds[tid * 4 + 0] = vv.x;
        vlds[tid * 4 + 1] = vv.y;
        vlds[tid * 4 + 2] = vv.z;
        unsigned* hrow = &hlds[tid * HWORDS];
        #pragma unroll
        for (int c = 0; c < 32; ++c)
            hrow[c] = F[(size_t)c * (size_t)n + i];
    }
    __syncthreads();

    const int rows = (int)(((blk_start + NPB) <= (long long)n) ? NPB : (n - blk_start));
    if (rows <= 0) return;
    const long long base = blk_start * 67ll;
    const int total = rows * 67;
    const unsigned short* hs = (const unsigned short*)hlds;
    for (int k = tid; k < total; k += NPB) {
        const int r = k / 67;
        const int c = k - r * 67;
        float val;
        if (c < 3) val = vlds[r * 4 + c];
        else       val = __uint_as_float((unsigned)hs[r * (2 * HWORDS) + (c - 3)] << 16);
        __builtin_nontemporal_store(val, &out[base + k]);
    }
}

// ---------------- fallback (if ws too small) ----------------
__device__ __forceinline__ void enc_level_f32(const float* __restrict__ tbl,
                                              float u, float v, float r,
                                              float& o0, float& o1)
{
    float pu = u * r, pv = v * r;
    float fu = floorf(pu), fv = floorf(pv);
    float au = pu - fu, av = pv - fv;
    unsigned cu = (unsigned)fu, cv = (unsigned)fv;
    unsigned h0 = cv * HASH_PRIME;
    unsigned h1 = (cv + 1u) * HASH_PRIME;
    unsigned i00 = (cu ^ h0) & TMASK;
    unsigned i01 = (cu ^ h1) & TMASK;
    unsigned i10 = ((cu + 1u) ^ h0) & TMASK;
    unsigned i11 = ((cu + 1u) ^ h1) & TMASK;
    vf2 g00 = *(const vf2*)(tbl + 2u * i00);
    vf2 g01 = *(const vf2*)(tbl + 2u * i01);
    vf2 g10 = *(const vf2*)(tbl + 2u * i10);
    vf2 g11 = *(const vf2*)(tbl + 2u * i11);
    float w00 = (1.f - au) * (1.f - av);
    float w01 = (1.f - au) * av;
    float w10 = au * (1.f - av);
    float w11 = au * av;
    o0 = w00 * g00.x + w01 * g01.x + w10 * g10.x + w11 * g11.x;
    o1 = w00 * g00.y + w01 * g01.y + w10 * g10.y + w11 * g11.y;
}

__global__ __launch_bounds__(NPB)
void hashprif_fallback(const float* __restrict__ x,
                       const float* __restrict__ t1,
                       const float* __restrict__ t2,
                       float* __restrict__ out,
                       int n)
{
    __shared__ unsigned hlds[NPB * (HSTRIDE / 2)];
    __shared__ float vlds[NPB * 4];
    const float res[16] = {16.f, 20.f, 25.f, 32.f, 40.f, 50.f, 64.f, 80.f,
                           101.f, 128.f, 161.f, 203.f, 256.f, 322.f, 406.f, 512.f};
    const int tid = threadIdx.x;
    const long long i = (long long)blockIdx.x * NPB + tid;
    const bool valid = i < (long long)n;

    if (valid) {
        const float* xi = x + i * 6ll;
        vf2 p0 = __builtin_nontemporal_load((const vf2*)(xi + 0));
        vf2 p1 = __builtin_nontemporal_load((const vf2*)(xi + 2));
        vf2 p2 = __builtin_nontemporal_load((const vf2*)(xi + 4));
        float ox = p0.x, oy = p0.y, oz = p1.x;
        float dx = p1.y - ox, dy = p2.x - oy, dz = p2.y - oz;
        float nd = sqrtf(dx * dx + dy * dy + dz * dz);
        float invd = 1.0f / fmaxf(nd, 1e-12f);
        dx *= invd; dy *= invd; dz *= invd;
        float th_d = acosf(fminf(fmaxf(dz, -1.f), 1.f));
        float ph_d = atan2f(dy, dx);
        float u_d = (th_d + 3.14159265358979323846f) / 6.28318530717958647692f;
        float v_d = (ph_d + 3.14159265358979323846f) / 6.28318530717958647692f;
        float cx = oy * dz - oz * dy;
        float cy = oz * dx - ox * dz;
        float cz = ox * dy - oy * dx;
        float vx = dy * cz - dz * cy;
        float vy = dz * cx - dx * cz;
        float vz = dx * cy - dy * cx;
        float nv = sqrtf(vx * vx + vy * vy + vz * vz);
        float invv = 1.0f / fmaxf(nv, 1e-12f);
        float wx = vx * invv, wy = vy * invv, wz = vz * invv;
        float th_v = acosf(fminf(fmaxf(wz, -1.f), 1.f));
        float ph_v = atan2f(wy, wx);
        float u_v = (th_v + 3.14159265358979323846f) / 6.28318530717958647692f;
        float v_v = (ph_v + 3.14159265358979323846f) / 6.28318530717958647692f;
        vlds[tid * 4 + 0] = vx;
        vlds[tid * 4 + 1] = vy;
        vlds[tid * 4 + 2] = vz;
        unsigned* hrow = &hlds[tid * (HSTRIDE / 2)];
        #pragma unroll
        for (int l = 0; l < 16; ++l) {
            float f0, f1;
            enc_level_f32(t1 + (size_t)l * 65536, u_d, v_d, res[l], f0, f1);
            hrow[l] = pack_bf16(f0, f1);
        }
        #pragma unroll
        for (int l = 0; l < 16; ++l) {
            float g0, g1;
            enc_level_f32(t2 + (size_t)l * 65536, u_v, v_v, res[l], g0, g1);
            hrow[16 + l] = pack_bf16(g0, g1);
        }
    }
    __syncthreads();
    const long long blk_start = (long long)blockIdx.x * NPB;
    const int rows = (int)(((blk_start + NPB) <= (long long)n) ? NPB : (n - blk_start));
    if (rows <= 0) return;
    const long long base = blk_start * 67ll;
    const int total = rows * 67;
    const unsigned short* hs = (const unsigned short*)hlds;
    for (int k = tid; k < total; k += NPB) {
        const int r = k / 67;
        const int c = k - r * 67;
        float val;
        if (c < 3) val = vlds[r * 4 + c];
        else {
            unsigned hv = (unsigned)hs[r * HSTRIDE + (c - 3)];
            val = __uint_as_float(hv << 16);
        }
        __builtin_nontemporal_store(val, &out[base + k]);
    }
}

extern "C" void kernel_launch(void* const* d_in, const int* in_sizes, int n_in,
                              void* d_out, int out_size, void* d_ws, size_t ws_size,
                              hipStream_t stream) {
    const float* x  = (const float*)d_in[0];
    const float* t1 = (const float*)d_in[1];
    const float* t2 = (const float*)d_in[2];
    float* out = (float*)d_out;
    const int n = in_sizes[0] / 6;
    const size_t nn = (size_t)n;
    // ws layout: cD[4n] | cV[4n] | vect[16n] | F[128n] | Tp[4MB]
    const size_t base_need = 152ull * nn;
    const size_t tp_bytes  = 32ull * 32768ull * 4ull;
    const size_t need_packed = base_need + tp_bytes;

    if (ws_size >= base_need) {
        unsigned* cD = (unsigned*)d_ws;
        unsigned* cV = cD + nn;
        vf4* vect = (vf4*)((char*)d_ws + 8ull * nn);
        unsigned* F = (unsigned*)((char*)d_ws + 24ull * nn);
        const bool packed = (ws_size >= need_packed);
        unsigned* Tp = packed ? (unsigned*)((char*)d_ws + base_need) : (unsigned*)nullptr;

        const int nbp = (n + 255) / 256;
        const int gpre = packed ? (nbp + 32) : nbp;
        hipLaunchKernelGGL(prepass, dim3(gpre), dim3(256), 0, stream,
                           x, t1, t2, cD, cV, vect, Tp, n, nbp);

        dim3 ga((n + CHUNK - 1) / CHUNK, 32);
        const bool full = (n % CHUNK == 0);
        if (full) {
            if (packed)
                hipLaunchKernelGGL(HIP_KERNEL_NAME(stageA<true, true>), ga, dim3(1024), 0, stream,
                                   t1, t2, Tp, cD, cV, F, n);
            else
                hipLaunchKernelGGL(HIP_KERNEL_NAME(stageA<true, false>), ga, dim3(1024), 0, stream,
                                   t1, t2, Tp, cD, cV, F, n);
            hipLaunchKernelGGL(stageB_t, dim3((n + NPB - 1) / NPB), dim3(NPB), 0, stream,
                               F, vect, out, n);
        } else {
            if (packed)
                hipLaunchKernelGGL(HIP_KERNEL_NAME(stageA<false, true>), ga, dim3(1024), 0, stream,
                                   t1, t2, Tp, cD, cV, F, n);
            else
                hipLaunchKernelGGL(HIP_KERNEL_NAME(stageA<false, false>), ga, dim3(1024), 0, stream,
                                   t1, t2, Tp, cD, cV, F, n);
            hipLaunchKernelGGL(stageB, dim3((n + NPB - 1) / NPB), dim3(NPB), 0, stream,
                               F, vect, out, n);
        }
    } else {
        hipLaunchKernelGGL(hashprif_fallback, dim3((n + NPB - 1) / NPB), dim3(NPB), 0, stream,
                           x, t1, t2, out, n);
    }
}

// Round 3
// 158.863 us; speedup vs baseline: 1.0953x; 1.0953x over previous
//
#include <hip/hip_runtime.h>
#include <math.h>

#define HASH_PRIME 2654435761u
#define TMASK 32767u
#define NPB 128
#define HWORDS 35           // unsigned per LDS row in stageB (odd -> conflict-free gather writes)
#define HSTRIDE 68          // ushorts per LDS row in fallback (legacy)
#define CHUNK 65536         // 16 x-chunks * 32 levels = 512 blocks = 2/CU (load balance + overlap)

typedef float vf2 __attribute__((ext_vector_type(2)));
typedef float vf4 __attribute__((ext_vector_type(4)));
typedef unsigned vu2 __attribute__((ext_vector_type(2)));

__device__ __forceinline__ unsigned pack_bf16(float a, float b) {
    return (__float_as_uint(a) >> 16) | (__float_as_uint(b) & 0xffff0000u);
}
__device__ __forceinline__ float bf_lo(unsigned w) { return __uint_as_float(w << 16); }
__device__ __forceinline__ float bf_hi(unsigned w) { return __uint_as_float(w & 0xffff0000u); }

// ---------------- kernel 1: coords + vect prepass (+ table bf16 pre-pack) ----------------
__global__ __launch_bounds__(256)
void prepass(const float* __restrict__ x,
             const float* __restrict__ t1, const float* __restrict__ t2,
             unsigned* __restrict__ cD, unsigned* __restrict__ cV,
             vf4* __restrict__ vect, unsigned* __restrict__ Tp,
             int n, int nbp)
{
    if ((int)blockIdx.x >= nbp) {
        const int tb = (int)blockIdx.x - nbp;
        const float* src = (tb < 16) ? (t1 + (size_t)tb * 65536)
                                     : (t2 + (size_t)(tb - 16) * 65536);
        const vf4* s4 = (const vf4*)src;
        vu2* dst = (vu2*)(Tp + (size_t)tb * 32768);
        #pragma unroll 8
        for (int j = 0; j < 64; ++j) {
            const int k = j * 256 + (int)threadIdx.x;
            vf4 e = s4[k];                       // entries 2k, 2k+1
            vu2 w; w.x = pack_bf16(e.x, e.y); w.y = pack_bf16(e.z, e.w);
            dst[k] = w;
        }
        return;
    }

    const int i = blockIdx.x * 256 + threadIdx.x;
    if (i >= n) return;
    const float* xi = x + (long long)i * 6;
    vf2 p0 = __builtin_nontemporal_load((const vf2*)(xi + 0));
    vf2 p1 = __builtin_nontemporal_load((const vf2*)(xi + 2));
    vf2 p2 = __builtin_nontemporal_load((const vf2*)(xi + 4));
    float ox = p0.x, oy = p0.y, oz = p1.x;
    float dx = p1.y - ox, dy = p2.x - oy, dz = p2.y - oz;

    float nd = sqrtf(dx * dx + dy * dy + dz * dz);
    float invd = 1.0f / fmaxf(nd, 1e-12f);
    dx *= invd; dy *= invd; dz *= invd;

    float th_d = acosf(fminf(fmaxf(dz, -1.f), 1.f));
    float ph_d = atan2f(dy, dx);
    float u_d = (th_d + 3.14159265358979323846f) / 6.28318530717958647692f;
    float v_d = (ph_d + 3.14159265358979323846f) / 6.28318530717958647692f;

    float cx = oy * dz - oz * dy;
    float cy = oz * dx - ox * dz;
    float cz = ox * dy - oy * dx;
    float vx = dy * cz - dz * cy;
    float vy = dz * cx - dx * cz;
    float vz = dx * cy - dy * cx;

    float nv = sqrtf(vx * vx + vy * vy + vz * vz);
    float invv = 1.0f / fmaxf(nv, 1e-12f);
    float wx = vx * invv, wy = vy * invv, wz = vz * invv;
    float th_v = acosf(fminf(fmaxf(wz, -1.f), 1.f));
    float ph_v = atan2f(wy, wx);
    float u_v = (th_v + 3.14159265358979323846f) / 6.28318530717958647692f;
    float v_v = (ph_v + 3.14159265358979323846f) / 6.28318530717958647692f;

    unsigned ud = (unsigned)fminf(fmaxf(u_d, 0.f) * 65536.f, 65535.f);
    unsigned vd = (unsigned)fminf(fmaxf(v_d, 0.f) * 65536.f, 65535.f);
    unsigned uv = (unsigned)fminf(fmaxf(u_v, 0.f) * 65536.f, 65535.f);
    unsigned vv_ = (unsigned)fminf(fmaxf(v_v, 0.f) * 65536.f, 65535.f);
    __builtin_nontemporal_store(ud | (vd << 16), &cD[i]);
    __builtin_nontemporal_store(uv | (vv_ << 16), &cV[i]);
    vf4 vo; vo.x = vx; vo.y = vy; vo.z = vz; vo.w = 0.f;
    __builtin_nontemporal_store(vo, &vect[i]);
}

// ---------------- kernel 2: per-(table,level) LDS-gather ----------------
__device__ __forceinline__ unsigned enc_point(const unsigned* __restrict__ tl,
                                              float rs, unsigned cw)
{
    float pu = (float)(cw & 0xffffu) * rs;
    float pv = (float)(cw >> 16) * rs;
    float fu = floorf(pu), fv = floorf(pv);
    float au = pu - fu, av = pv - fv;
    unsigned cu = (unsigned)fu, cv = (unsigned)fv;
    unsigned h0 = cv * HASH_PRIME;
    unsigned h1 = (cv + 1u) * HASH_PRIME;
    unsigned w00 = tl[(cu ^ h0) & TMASK];
    unsigned w01 = tl[(cu ^ h1) & TMASK];
    unsigned w10 = tl[((cu + 1u) ^ h0) & TMASK];
    unsigned w11 = tl[((cu + 1u) ^ h1) & TMASK];
    float a00 = (1.f - au) * (1.f - av);
    float a01 = (1.f - au) * av;
    float a10 = au * (1.f - av);
    float a11 = au * av;
    float o0 = a00 * bf_lo(w00) + a01 * bf_lo(w01) + a10 * bf_lo(w10) + a11 * bf_lo(w11);
    float o1 = a00 * bf_hi(w00) + a01 * bf_hi(w01) + a10 * bf_hi(w10) + a11 * bf_hi(w11);
    return pack_bf16(o0, o1);
}

template<bool FULL, bool PACKED>
__global__ __launch_bounds__(1024)
void stageA(const float* __restrict__ t1, const float* __restrict__ t2,
            const unsigned* __restrict__ Tp,
            const unsigned* __restrict__ cD, const unsigned* __restrict__ cV,
            unsigned* __restrict__ F, int n)
{
    __shared__ unsigned tl[32768];        // whole level table, bf16-pair packed (128 KB)
    // longest-job-first: first 256 dispatched blocks = 8 finest levels of BOTH tables
    // -> every CU runs one expensive + one cheap block (optimal makespan)
    const int y = blockIdx.y;
    const int tb = (y & 1) * 16 + (15 - (y >> 1));
    const float resv[16] = {16.f, 20.f, 25.f, 32.f, 40.f, 50.f, 64.f, 80.f,
                            101.f, 128.f, 161.f, 203.f, 256.f, 322.f, 406.f, 512.f};
    const float rs = resv[tb & 15] * (1.f / 65536.f);

    if constexpr (PACKED) {
        // straight 128 KB copy of the pre-packed level table (half bytes, no VALU pack)
        const vf4* s4 = (const vf4*)(Tp + (size_t)tb * 32768);
        vf4* tl4 = (vf4*)tl;
        #pragma unroll
        for (int j = 0; j < 8; ++j) {
            const int k = j * 1024 + threadIdx.x;
            tl4[k] = s4[k];
        }
    } else {
        const float* src = (tb < 16) ? (t1 + (size_t)tb * 65536)
                                     : (t2 + (size_t)(tb - 16) * 65536);
        const vf4* src4 = (const vf4*)src;
        vu2* tl2 = (vu2*)tl;
        #pragma unroll
        for (int j = 0; j < 16; ++j) {
            const int k = j * 1024 + threadIdx.x;
            vf4 e = src4[k];
            vu2 w; w.x = pack_bf16(e.x, e.y); w.y = pack_bf16(e.z, e.w);
            tl2[k] = w;
        }
    }
    __syncthreads();

    const unsigned* cc = (tb < 16) ? cD : cV;   // plain loads: L2/L3-reused x16
    unsigned* Fo = F + (size_t)tb * (size_t)n;  // linear per-level stream (disjoint 4MB regions)
    const int ibase = blockIdx.x * CHUNK + threadIdx.x;

    if (FULL) {
        // guard-free: n % CHUNK == 0; 4-point batches, 2 batches in flight
        #pragma unroll 2
        for (int k = 0; k < CHUNK / 1024; k += 4) {
            const int i0 = ibase + (k + 0) * 1024;
            const int i1 = ibase + (k + 1) * 1024;
            const int i2 = ibase + (k + 2) * 1024;
            const int i3 = ibase + (k + 3) * 1024;
            unsigned c0 = cc[i0];
            unsigned c1 = cc[i1];
            unsigned c2 = cc[i2];
            unsigned c3 = cc[i3];
            unsigned r0 = enc_point(tl, rs, c0);
            unsigned r1 = enc_point(tl, rs, c1);
            unsigned r2 = enc_point(tl, rs, c2);
            unsigned r3 = enc_point(tl, rs, c3);
            Fo[i0] = r0;
            Fo[i1] = r1;
            Fo[i2] = r2;
            Fo[i3] = r3;
        }
    } else {
        #pragma unroll 4
        for (int k = 0; k < CHUNK / 1024; ++k) {
            const int i = ibase + k * 1024;
            if (i < n) {
                unsigned c = cc[i];
                Fo[i] = enc_point(tl, rs, c);
            }
        }
    }
}

// ---------------- kernel 3: transpose + coalesced dwordx4 writeout ----------------
__global__ __launch_bounds__(NPB)
void stageB(const unsigned* __restrict__ F, const vf4* __restrict__ vect,
            float* __restrict__ out, int n)
{
    __shared__ unsigned hlds[NPB * HWORDS];   // row stride 35 words (odd) -> conflict-free writes
    __shared__ float vlds[NPB * 5];           // stride 5 (odd) -> conflict-free
    const int tid = threadIdx.x;
    const long long blk_start = (long long)blockIdx.x * NPB;
    const long long i = blk_start + tid;
    if (i < (long long)n) {
        vf4 vv = vect[i];
        vlds[tid * 5 + 0] = vv.x;
        vlds[tid * 5 + 1] = vv.y;
        vlds[tid * 5 + 2] = vv.z;
        unsigned* hrow = &hlds[tid * HWORDS];
        #pragma unroll
        for (int c = 0; c < 32; ++c)
            hrow[c] = F[(size_t)c * (size_t)n + i];   // plain: partially L2/L3-resident
    }
    __syncthreads();

    const int rows = (int)(((blk_start + NPB) <= (long long)n) ? NPB : (n - blk_start));
    if (rows <= 0) return;
    const long long base = blk_start * 67ll;
    const int total = rows * 67;
    const unsigned short* hs = (const unsigned short*)hlds;

    // vectorized 16B path: base is 16B-aligned (128*67*4 = 34304 = 16*2144)
    const int nq = total >> 2;
    vf4* out4 = (vf4*)(out + base);
    for (int k = tid; k < nq; k += NPB) {
        vf4 o;
        #pragma unroll
        for (int j = 0; j < 4; ++j) {
            const int e = 4 * k + j;
            const int r = e / 67;             // magic-mul
            const int c = e - r * 67;
            float val;
            if (c < 3) val = vlds[r * 5 + c];
            else       val = __uint_as_float((unsigned)hs[r * (2 * HWORDS) + (c - 3)] << 16);
            o[j] = val;
        }
        __builtin_nontemporal_store(o, &out4[k]);
    }
    // scalar tail (only for a partial last block)
    for (int e = (nq << 2) + tid; e < total; e += NPB) {
        const int r = e / 67;
        const int c = e - r * 67;
        float val = (c < 3) ? vlds[r * 5 + c]
                            : __uint_as_float((unsigned)hs[r * (2 * HWORDS) + (c - 3)] << 16);
        __builtin_nontemporal_store(val, &out[base + e]);
    }
}

// ---------------- fallback (if ws too small) ----------------
__device__ __forceinline__ void enc_level_f32(const float* __restrict__ tbl,
                                              float u, float v, float r,
                                              float& o0, float& o1)
{
    float pu = u * r, pv = v * r;
    float fu = floorf(pu), fv = floorf(pv);
    float au = pu - fu, av = pv - fv;
    unsigned cu = (unsigned)fu, cv = (unsigned)fv;
    unsigned h0 = cv * HASH_PRIME;
    unsigned h1 = (cv + 1u) * HASH_PRIME;
    unsigned i00 = (cu ^ h0) & TMASK;
    unsigned i01 = (cu ^ h1) & TMASK;
    unsigned i10 = ((cu + 1u) ^ h0) & TMASK;
    unsigned i11 = ((cu + 1u) ^ h1) & TMASK;
    vf2 g00 = *(const vf2*)(tbl + 2u * i00);
    vf2 g01 = *(const vf2*)(tbl + 2u * i01);
    vf2 g10 = *(const vf2*)(tbl + 2u * i10);
    vf2 g11 = *(const vf2*)(tbl + 2u * i11);
    float w00 = (1.f - au) * (1.f - av);
    float w01 = (1.f - au) * av;
    float w10 = au * (1.f - av);
    float w11 = au * av;
    o0 = w00 * g00.x + w01 * g01.x + w10 * g10.x + w11 * g11.x;
    o1 = w00 * g00.y + w01 * g01.y + w10 * g10.y + w11 * g11.y;
}

__global__ __launch_bounds__(NPB)
void hashprif_fallback(const float* __restrict__ x,
                       const float* __restrict__ t1,
                       const float* __restrict__ t2,
                       float* __restrict__ out,
                       int n)
{
    __shared__ unsigned hlds[NPB * (HSTRIDE / 2)];
    __shared__ float vlds[NPB * 4];
    const float res[16] = {16.f, 20.f, 25.f, 32.f, 40.f, 50.f, 64.f, 80.f,
                           101.f, 128.f, 161.f, 203.f, 256.f, 322.f, 406.f, 512.f};
    const int tid = threadIdx.x;
    const long long i = (long long)blockIdx.x * NPB + tid;
    const bool valid = i < (long long)n;

    if (valid) {
        const float* xi = x + i * 6ll;
        vf2 p0 = __builtin_nontemporal_load((const vf2*)(xi + 0));
        vf2 p1 = __builtin_nontemporal_load((const vf2*)(xi + 2));
        vf2 p2 = __builtin_nontemporal_load((const vf2*)(xi + 4));
        float ox = p0.x, oy = p0.y, oz = p1.x;
        float dx = p1.y - ox, dy = p2.x - oy, dz = p2.y - oz;
        float nd = sqrtf(dx * dx + dy * dy + dz * dz);
        float invd = 1.0f / fmaxf(nd, 1e-12f);
        dx *= invd; dy *= invd; dz *= invd;
        float th_d = acosf(fminf(fmaxf(dz, -1.f), 1.f));
        float ph_d = atan2f(dy, dx);
        float u_d = (th_d + 3.14159265358979323846f) / 6.28318530717958647692f;
        float v_d = (ph_d + 3.14159265358979323846f) / 6.28318530717958647692f;
        float cx = oy * dz - oz * dy;
        float cy = oz * dx - ox * dz;
        float cz = ox * dy - oy * dx;
        float vx = dy * cz - dz * cy;
        float vy = dz * cx - dx * cz;
        float vz = dx * cy - dy * cx;
        float nv = sqrtf(vx * vx + vy * vy + vz * vz);
        float invv = 1.0f / fmaxf(nv, 1e-12f);
        float wx = vx * invv, wy = vy * invv, wz = vz * invv;
        float th_v = acosf(fminf(fmaxf(wz, -1.f), 1.f));
        float ph_v = atan2f(wy, wx);
        float u_v = (th_v + 3.14159265358979323846f) / 6.28318530717958647692f;
        float v_v = (ph_v + 3.14159265358979323846f) / 6.28318530717958647692f;
        vlds[tid * 4 + 0] = vx;
        vlds[tid * 4 + 1] = vy;
        vlds[tid * 4 + 2] = vz;
        unsigned* hrow = &hlds[tid * (HSTRIDE / 2)];
        #pragma unroll
        for (int l = 0; l < 16; ++l) {
            float f0, f1;
            enc_level_f32(t1 + (size_t)l * 65536, u_d, v_d, res[l], f0, f1);
            hrow[l] = pack_bf16(f0, f1);
        }
        #pragma unroll
        for (int l = 0; l < 16; ++l) {
            float g0, g1;
            enc_level_f32(t2 + (size_t)l * 65536, u_v, v_v, res[l], g0, g1);
            hrow[16 + l] = pack_bf16(g0, g1);
        }
    }
    __syncthreads();
    const long long blk_start = (long long)blockIdx.x * NPB;
    const int rows = (int)(((blk_start + NPB) <= (long long)n) ? NPB : (n - blk_start));
    if (rows <= 0) return;
    const long long base = blk_start * 67ll;
    const int total = rows * 67;
    const unsigned short* hs = (const unsigned short*)hlds;
    for (int k = tid; k < total; k += NPB) {
        const int r = k / 67;
        const int c = k - r * 67;
        float val;
        if (c < 3) val = vlds[r * 4 + c];
        else {
            unsigned hv = (unsigned)hs[r * HSTRIDE + (c - 3)];
            val = __uint_as_float(hv << 16);
        }
        __builtin_nontemporal_store(val, &out[base + k]);
    }
}

extern "C" void kernel_launch(void* const* d_in, const int* in_sizes, int n_in,
                              void* d_out, int out_size, void* d_ws, size_t ws_size,
                              hipStream_t stream) {
    const float* x  = (const float*)d_in[0];
    const float* t1 = (const float*)d_in[1];
    const float* t2 = (const float*)d_in[2];
    float* out = (float*)d_out;
    const int n = in_sizes[0] / 6;
    const size_t nn = (size_t)n;
    // ws layout: cD[4n] | cV[4n] | vect[16n] | F[128n] | Tp[4MB]
    const size_t base_need = 152ull * nn;
    const size_t tp_bytes  = 32ull * 32768ull * 4ull;
    const size_t need_packed = base_need + tp_bytes;

    if (ws_size >= base_need) {
        unsigned* cD = (unsigned*)d_ws;
        unsigned* cV = cD + nn;
        vf4* vect = (vf4*)((char*)d_ws + 8ull * nn);
        unsigned* F = (unsigned*)((char*)d_ws + 24ull * nn);
        const bool packed = (ws_size >= need_packed);
        unsigned* Tp = packed ? (unsigned*)((char*)d_ws + base_need) : (unsigned*)nullptr;

        const int nbp = (n + 255) / 256;
        const int gpre = packed ? (nbp + 32) : nbp;
        hipLaunchKernelGGL(prepass, dim3(gpre), dim3(256), 0, stream,
                           x, t1, t2, cD, cV, vect, Tp, n, nbp);

        dim3 ga((n + CHUNK - 1) / CHUNK, 32);
        const bool full = (n % CHUNK == 0);
        if (full) {
            if (packed)
                hipLaunchKernelGGL(HIP_KERNEL_NAME(stageA<true, true>), ga, dim3(1024), 0, stream,
                                   t1, t2, Tp, cD, cV, F, n);
            else
                hipLaunchKernelGGL(HIP_KERNEL_NAME(stageA<true, false>), ga, dim3(1024), 0, stream,
                                   t1, t2, Tp, cD, cV, F, n);
        } else {
            if (packed)
                hipLaunchKernelGGL(HIP_KERNEL_NAME(stageA<false, true>), ga, dim3(1024), 0, stream,
                                   t1, t2, Tp, cD, cV, F, n);
            else
                hipLaunchKernelGGL(HIP_KERNEL_NAME(stageA<false, false>), ga, dim3(1024), 0, stream,
                                   t1, t2, Tp, cD, cV, F, n);
        }
        hipLaunchKernelGGL(stageB, dim3((n + NPB - 1) / NPB), dim3(NPB), 0, stream,
                           F, vect, out, n);
    } else {
        hipLaunchKernelGGL(hashprif_fallback, dim3((n + NPB - 1) / NPB), dim3(NPB), 0, stream,
                           x, t1, t2, out, n);
    }
}